// Round 1
// baseline (2636.889 us; speedup 1.0000x reference)
//
#include <hip/hip_runtime.h>
#include <hip/hip_bf16.h>

#define SEQn 70
#define Bn 128
#define En 512
#define Hn 1024
#define Vn 10000
#define VPADn 10240
#define Mn (SEQn*Bn)      // 8960
#define H3n (3*Hn)        // 3072

typedef __hip_bfloat16 bf16;
typedef __attribute__((ext_vector_type(8))) short short8;
typedef __attribute__((ext_vector_type(4))) float f32x4;

__device__ __forceinline__ bf16 f2bf(float x){ return __float2bfloat16(x); }
__device__ __forceinline__ float bf2f(bf16 x){ return __bfloat162float(x); }

__device__ __forceinline__ void gl_lds16(const void* g, void* l){
  __builtin_amdgcn_global_load_lds((const __attribute__((address_space(1))) unsigned int*)g,
                                   (__attribute__((address_space(3))) unsigned int*)l, 16, 0, 0);
}

// ---------------- small prep kernels ----------------

__global__ void cat3_w(const float* __restrict__ a, const float* __restrict__ b,
                       const float* __restrict__ c, bf16* __restrict__ d, int n){
  int i = blockIdx.x * 256 + threadIdx.x;
  if (i >= 3*n) return;
  const float* s = (i < n) ? a : ((i < 2*n) ? b : c);
  int off = (i < n) ? i : ((i < 2*n) ? i - n : i - 2*n);
  d[i] = f2bf(s[off]);
}

__global__ void cat3_f(const float* __restrict__ a, const float* __restrict__ b,
                       const float* __restrict__ c, float* __restrict__ d, int n){
  int i = blockIdx.x * 256 + threadIdx.x;
  if (i >= 3*n) return;
  d[i] = (i < n) ? a[i] : ((i < 2*n) ? b[i - n] : c[i - 2*n]);
}

__global__ void f2b_k(const float* __restrict__ s, bf16* __restrict__ d, int n){
  int i = blockIdx.x * 256 + threadIdx.x;
  if (i < n) d[i] = f2bf(s[i]);
}

__global__ void conv_outw(const float* __restrict__ s, bf16* __restrict__ d){
  long i = (long)blockIdx.x * 256 + threadIdx.x;
  if (i >= (long)VPADn * Hn) return;
  int row = (int)(i >> 10);
  d[i] = (row < Vn) ? f2bf(s[i]) : f2bf(0.f);
}

__global__ void embed_k(const int* __restrict__ idx, const float* __restrict__ eW,
                        bf16* __restrict__ out){
  const int sb = blockIdx.x;
  const int t = idx[sb];
  const float* s = eW + (long)t * En;
  bf16* d = out + (long)sb * En;
  for (int e = threadIdx.x; e < En; e += 256) d[e] = f2bf(s[e]);
}

// ---------------- GEMM: C[M,N] = A[M,K] * B[N,K]^T + bias ----------------
// 128x128 tile, BK=64, 4 waves of 64x64, mfma_f32_16x16x32_bf16.
// LDS XOR-swizzle (16B unit ^= row&7) applied on source addr (staging) and read.

template<bool OB, bool NB>
__global__ __launch_bounds__(256)
void gemm_bt(const bf16* __restrict__ A, const bf16* __restrict__ Bm,
             const float* __restrict__ bias, void* __restrict__ C,
             int K, int ldc, int nvalid)
{
  __shared__ __align__(16) bf16 As[128*64];
  __shared__ __align__(16) bf16 Bs[128*64];
  const int tid = threadIdx.x;
  const int l = tid & 63, w = tid >> 6;
  const int lr = l & 15, lk = l >> 4;
  const int wm = (w >> 1) * 64, wn = (w & 1) * 64;
  const int mt = blockIdx.y, nt = blockIdx.x;
  const bf16* Ag = A + (long)mt * 128 * K;
  const bf16* Bg = Bm + (long)nt * 128 * K;

  f32x4 acc[4][4] = {};

  for (int kb = 0; kb < K; kb += 64) {
#pragma unroll
    for (int r = 0; r < 4; ++r) {
      const int u = r * 256 + tid;
      const int row = u >> 3, kus = (u & 7) ^ (row & 7);
      gl_lds16(Ag + (long)row * K + kb + kus * 8, (char*)As + (r * 256 + w * 64) * 16);
    }
#pragma unroll
    for (int r = 0; r < 4; ++r) {
      const int u = r * 256 + tid;
      const int row = u >> 3, kus = (u & 7) ^ (row & 7);
      gl_lds16(Bg + (long)row * K + kb + kus * 8, (char*)Bs + (r * 256 + w * 64) * 16);
    }
    __syncthreads();
#pragma unroll
    for (int kh = 0; kh < 2; ++kh) {
      const int ku = kh * 4 + lk;
      short8 af[4], bfv[4];
#pragma unroll
      for (int i = 0; i < 4; ++i) {
        const int ar = wm + i * 16 + lr;
        af[i]  = *(const short8*)((const char*)As + ar * 128 + ((ku ^ (ar & 7)) * 16));
        const int br = wn + i * 16 + lr;
        bfv[i] = *(const short8*)((const char*)Bs + br * 128 + ((ku ^ (br & 7)) * 16));
      }
#pragma unroll
      for (int i = 0; i < 4; ++i)
#pragma unroll
        for (int j = 0; j < 4; ++j)
          acc[i][j] = __builtin_amdgcn_mfma_f32_16x16x32_bf16(af[i], bfv[j], acc[i][j], 0, 0, 0);
    }
    __syncthreads();
  }

#pragma unroll
  for (int i = 0; i < 4; ++i) {
#pragma unroll
    for (int j = 0; j < 4; ++j) {
      const int col = nt * 128 + wn + j * 16 + lr;
      const bool cok = (!NB) || (col < nvalid);
      const float bv = cok ? bias[col] : 0.f;
      const int row = mt * 128 + wm + i * 16 + lk * 4;
      if (cok) {
#pragma unroll
        for (int r = 0; r < 4; ++r) {
          const float v = acc[i][j][r] + bv;
          if (OB) ((bf16*)C)[(long)(row + r) * ldc + col] = f2bf(v);
          else    ((float*)C)[(long)(row + r) * ldc + col] = v;
        }
      }
    }
  }
}

// ---------------- fused GRU step ----------------
// grid 64 blocks: each block computes 16 hidden cols x 128 batch rows for all
// 3 gates (hW = h @ Wh_cat^T slice), then the elementwise GRU update.

__global__ __launch_bounds__(256)
void gru_step(const bf16* __restrict__ hb, const float* __restrict__ hf,
              const bf16* __restrict__ Wh, const bf16* __restrict__ xg,
              bf16* __restrict__ hb_out, float* __restrict__ hf_out,
              float* __restrict__ hT)
{
  __shared__ __align__(16) bf16 As[128*64];
  __shared__ __align__(16) bf16 Bs[3*16*64];
  const int tid = threadIdx.x;
  const int l = tid & 63, w = tid >> 6;
  const int lr = l & 15, lk = l >> 4;
  const int nb = blockIdx.x;

  f32x4 acc[3][2] = {};

  for (int kb = 0; kb < Hn; kb += 64) {
#pragma unroll
    for (int r = 0; r < 4; ++r) {
      const int u = r * 256 + tid;
      const int row = u >> 3, kus = (u & 7) ^ (row & 7);
      gl_lds16(hb + (long)row * Hn + kb + kus * 8, (char*)As + (r * 256 + w * 64) * 16);
    }
    {
      const int u = tid;
      const int r16 = u >> 3, kus = (u & 7) ^ (r16 & 7);
      const int g = r16 >> 4, rr = r16 & 15;
      gl_lds16(Wh + (long)(g * Hn + nb * 16 + rr) * Hn + kb + kus * 8,
               (char*)Bs + (w * 64) * 16);
      if (w < 2) {
        const int u2 = 256 + tid;
        const int r16b = u2 >> 3, kusb = (u2 & 7) ^ (r16b & 7);
        const int gb = r16b >> 4, rrb = r16b & 15;
        gl_lds16(Wh + (long)(gb * Hn + nb * 16 + rrb) * Hn + kb + kusb * 8,
                 (char*)Bs + (256 + w * 64) * 16);
      }
    }
    __syncthreads();
#pragma unroll
    for (int kh = 0; kh < 2; ++kh) {
      const int ku = kh * 4 + lk;
      short8 af[2], bg[3];
#pragma unroll
      for (int i = 0; i < 2; ++i) {
        const int ar = w * 32 + i * 16 + lr;
        af[i] = *(const short8*)((const char*)As + ar * 128 + ((ku ^ (ar & 7)) * 16));
      }
#pragma unroll
      for (int g = 0; g < 3; ++g) {
        const int br = g * 16 + lr;
        bg[g] = *(const short8*)((const char*)Bs + br * 128 + ((ku ^ (lr & 7)) * 16));
      }
#pragma unroll
      for (int g = 0; g < 3; ++g)
#pragma unroll
        for (int i = 0; i < 2; ++i)
          acc[g][i] = __builtin_amdgcn_mfma_f32_16x16x32_bf16(af[i], bg[g], acc[g][i], 0, 0, 0);
    }
    __syncthreads();
  }

#pragma unroll
  for (int i = 0; i < 2; ++i) {
    const int row0 = w * 32 + i * 16 + lk * 4;
    const int col = nb * 16 + lr;
#pragma unroll
    for (int r = 0; r < 4; ++r) {
      const int rw = row0 + r;
      const float xr = bf2f(xg[rw * H3n + col]);
      const float xz = bf2f(xg[rw * H3n + Hn + col]);
      const float xh = bf2f(xg[rw * H3n + 2 * Hn + col]);
      const float hv = hf[rw * Hn + col];
      const float rg = 1.f / (1.f + __expf(-(xr + acc[0][i][r])));
      const float zg = 1.f / (1.f + __expf(-(xz + acc[1][i][r])));
      const float h1 = tanhf(xh + rg * acc[2][i][r]);
      const float hn = (1.f - zg) * h1 + zg * hv;
      hf_out[rw * Hn + col] = hn;
      hb_out[rw * Hn + col] = f2bf(hn);
      if (hT) hT[rw * Hn + col] = hn;
    }
  }
}

// ---------------- launch ----------------

extern "C" void kernel_launch(void* const* d_in, const int* in_sizes, int n_in,
                              void* d_out, int out_size, void* d_ws, size_t ws_size,
                              hipStream_t stream)
{
  (void)in_sizes; (void)n_in; (void)out_size; (void)ws_size;
  const int*   inp    = (const int*)d_in[0];
  const float* hidden = (const float*)d_in[1];
  const float* embW   = (const float*)d_in[2];
  const float* outW   = (const float*)d_in[3];
  const float* outb   = (const float*)d_in[4];

  char* p = (char*)d_ws;
  auto take = [&](size_t n){ char* q = p; p += (n + 255) & ~(size_t)255; return q; };
  bf16*  l0Wi = (bf16*) take((size_t)H3n*En*2);
  bf16*  l0Wh = (bf16*) take((size_t)H3n*Hn*2);
  bf16*  l1Wi = (bf16*) take((size_t)H3n*Hn*2);
  bf16*  l1Wh = (bf16*) take((size_t)H3n*Hn*2);
  bf16*  oW   = (bf16*) take((size_t)VPADn*Hn*2);
  float* b0   = (float*)take((size_t)H3n*4);
  float* b1   = (float*)take((size_t)H3n*4);
  bf16*  emb  = (bf16*) take((size_t)Mn*En*2);
  bf16*  xg   = (bf16*) take((size_t)Mn*H3n*2);
  bf16*  ys0  = (bf16*) take((size_t)Mn*Hn*2);
  bf16*  ys1  = (bf16*) take((size_t)Mn*Hn*2);
  bf16*  h0b  = (bf16*) take((size_t)Bn*Hn*2);
  bf16*  h1b  = (bf16*) take((size_t)Bn*Hn*2);
  float* hfA  = (float*)take((size_t)Bn*Hn*4);
  float* hfB  = (float*)take((size_t)Bn*Hn*4);

  // weight/bias prep (bf16, gate-concatenated [r;z;h])
  cat3_w<<<dim3((3*Hn*En+255)/256),256,0,stream>>>((const float*)d_in[5],(const float*)d_in[6],(const float*)d_in[7], l0Wi, Hn*En);
  cat3_w<<<dim3((3*Hn*Hn+255)/256),256,0,stream>>>((const float*)d_in[8],(const float*)d_in[9],(const float*)d_in[10], l0Wh, Hn*Hn);
  cat3_w<<<dim3((3*Hn*Hn+255)/256),256,0,stream>>>((const float*)d_in[14],(const float*)d_in[15],(const float*)d_in[16], l1Wi, Hn*Hn);
  cat3_w<<<dim3((3*Hn*Hn+255)/256),256,0,stream>>>((const float*)d_in[17],(const float*)d_in[18],(const float*)d_in[19], l1Wh, Hn*Hn);
  conv_outw<<<dim3((unsigned)(((long)VPADn*Hn+255)/256)),256,0,stream>>>(outW, oW);
  cat3_f<<<dim3((H3n+255)/256),256,0,stream>>>((const float*)d_in[11],(const float*)d_in[12],(const float*)d_in[13], b0, Hn);
  cat3_f<<<dim3((H3n+255)/256),256,0,stream>>>((const float*)d_in[20],(const float*)d_in[21],(const float*)d_in[22], b1, Hn);
  f2b_k<<<dim3((Bn*Hn+255)/256),256,0,stream>>>(hidden, h0b, Bn*Hn);
  f2b_k<<<dim3((Bn*Hn+255)/256),256,0,stream>>>(hidden + Bn*Hn, h1b, Bn*Hn);
  embed_k<<<dim3(Mn),256,0,stream>>>(inp, embW, emb);

  // ---- layer 0 ----
  gemm_bt<true,false><<<dim3(H3n/128, Mn/128),256,0,stream>>>(emb, l0Wi, b0, xg, En, H3n, H3n);
  {
    const bf16* hb = h0b; const float* hf = hidden;
    for (int t = 0; t < SEQn; ++t) {
      bf16*  hbo = ys0 + (size_t)t*Bn*Hn;
      float* hfo = (t & 1) ? hfB : hfA;
      float* hT  = (t == SEQn-1) ? ((float*)d_out + (size_t)SEQn*Bn*Vn) : nullptr;
      gru_step<<<dim3(Hn/16),256,0,stream>>>(hb, hf, l0Wh, xg + (size_t)t*Bn*H3n, hbo, hfo, hT);
      hb = hbo; hf = hfo;
    }
  }
  // ---- layer 1 ----
  gemm_bt<true,false><<<dim3(H3n/128, Mn/128),256,0,stream>>>(ys0, l1Wi, b1, xg, Hn, H3n, H3n);
  {
    const bf16* hb = h1b; const float* hf = hidden + Bn*Hn;
    for (int t = 0; t < SEQn; ++t) {
      bf16*  hbo = ys1 + (size_t)t*Bn*Hn;
      float* hfo = (t & 1) ? hfB : hfA;
      float* hT  = (t == SEQn-1) ? ((float*)d_out + (size_t)SEQn*Bn*Vn + (size_t)Bn*Hn) : nullptr;
      gru_step<<<dim3(Hn/16),256,0,stream>>>(hb, hf, l1Wh, xg + (size_t)t*Bn*H3n, hbo, hfo, hT);
      hb = hbo; hf = hfo;
    }
  }
  // ---- logits ----
  gemm_bt<false,true><<<dim3(VPADn/128, Mn/128),256,0,stream>>>(ys1, oW, outb, d_out, Hn, Vn, Vn);
}